// Round 2
// baseline (1080.803 us; speedup 1.0000x reference)
//
#include <hip/hip_runtime.h>

// GCN decoder: batched deterministic radix partition (LDS-staged scatter, 512x1024) ->
// in-place per-node CSR -> float4 register gather; fp32 GEMMs.
// upsample2 identity: h = upsample2(x) @ W has h[2i]==h[2i+1] -> compute h on the
// pre-upsample node set, index with (node >> HSHIFT).
// R12 post-mortem: 8x8 microtile dbuf ballooned to 180 VGPR @ 392 blocks -> 8.4% occ, 98us.
// R13 gemm_mn: MRx8 microtile (MR in {2,4}), acc <= 32 regs, __launch_bounds__(256,4)
// caps VGPR at 128 (16 waves/CU); tiles sized so every layer launches >= 782 blocks.
// Same proven 1-sync/tile dbuf loop. gemm_t was LDS-BW-bound (2 B/FMA -> 44% VALU cap);
// L1 at 1.5 B/FMA + 16 waves/CU targets ~60% VALU -> ~40us.

static inline int cdiv(long a, int b) { return (int)((a + b - 1) / b); }
static constexpr int NBLK = 512;  // partition chunks / histogram columns

// ---------------- hist: per-chunk histogram (bucket-major table) ----------------
__global__ __launch_bounds__(1024) void part_hist3_kernel(
    const int* __restrict__ d1, const int* __restrict__ d2, const int* __restrict__ d3,
    int* __restrict__ histG, int E1, int E12, int ET, int chunk, int NBall, int B2, int B3) {
  __shared__ int hist[688];
  for (int i = threadIdx.x; i < NBall; i += 1024) hist[i] = 0;
  __syncthreads();
  const int k = blockIdx.x;
  const int lo = k * chunk, hi = min(ET, lo + chunk);
  for (int e = lo + (int)threadIdx.x; e < hi; e += 1024) {
    int l, ee;
    if (e < E1) { l = 0; ee = e; }
    else if (e < E12) { l = 1; ee = e - E1; }
    else { l = 2; ee = e - E12; }
    const int* dp = (l == 0) ? d1 : (l == 1) ? d2 : d3;
    int base = (l == 0) ? 0 : (l == 1) ? B2 : B3;
    atomicAdd(&hist[base + (dp[ee] >> 8)], 1);
  }
  __syncthreads();
  for (int i = threadIdx.x; i < NBall; i += 1024) histG[i * NBLK + k] = hist[i];
}

__global__ __launch_bounds__(1024) void part_hist4_kernel(const int* __restrict__ dst,
                                                          int* __restrict__ histG,
                                                          int E, int chunk, int NBall) {
  __shared__ int hist[784];
  for (int i = threadIdx.x; i < NBall; i += 1024) hist[i] = 0;
  __syncthreads();
  const int k = blockIdx.x;
  const int lo = k * chunk, hi = min(E, lo + chunk);
  for (int e = lo + (int)threadIdx.x; e < hi; e += 1024)
    atomicAdd(&hist[dst[e] >> 8], 1);
  __syncthreads();
  for (int i = threadIdx.x; i < NBall; i += 1024) histG[i * NBLK + k] = hist[i];
}

// ---------------- scan primitives (in-place safe) ----------------
__global__ void scan_block_kernel(const int* __restrict__ in, int* __restrict__ outv,
                                  int* __restrict__ psum, int n) {
  __shared__ int tmp[256];
  int i = blockIdx.x * 256 + threadIdx.x;
  int v = (i < n) ? in[i] : 0;
  tmp[threadIdx.x] = v;
  __syncthreads();
  for (int off = 1; off < 256; off <<= 1) {
    int t = (threadIdx.x >= off) ? tmp[threadIdx.x - off] : 0;
    __syncthreads();
    tmp[threadIdx.x] += t;
    __syncthreads();
  }
  if (i < n) outv[i] = tmp[threadIdx.x] - v;
  if (threadIdx.x == 255) psum[blockIdx.x] = tmp[255];
}

__global__ __launch_bounds__(1024) void scan_psum_kernel(int* __restrict__ psum, int nb) {
  __shared__ int tmp[1024];
  int i = threadIdx.x;
  int v = (i < nb) ? psum[i] : 0;
  tmp[i] = v;
  __syncthreads();
  for (int off = 1; off < 1024; off <<= 1) {
    int t = (i >= off) ? tmp[i - off] : 0;
    __syncthreads();
    tmp[i] += t;
    __syncthreads();
  }
  if (i < nb) psum[i] = tmp[i] - v;
}

__global__ void scan_add_kernel(int* __restrict__ v, const int* __restrict__ psum, int n) {
  int i = blockIdx.x * 256 + threadIdx.x;
  if (i < n) v[i] += psum[blockIdx.x];
}

// boffs[g] = scanned histG[g*NBLK]; boffs[NBall] = Etot
__global__ void extract_offs_kernel(const int* __restrict__ histG, int* __restrict__ boffs,
                                    int NBall, int Etot) {
  int i = blockIdx.x * 256 + threadIdx.x;
  if (i < NBall) boffs[i] = histG[i * NBLK];
  if (i == NBall) boffs[NBall] = Etot;
}

// ---------------- LDS-staged scatter (1024 threads): stage chunk, flush contiguous ----------
template <int CHUNK, int NBCAP>
__global__ __launch_bounds__(1024) void part_scatter3_staged(
    const int* __restrict__ s1, const int* __restrict__ d1,
    const int* __restrict__ s2, const int* __restrict__ d2,
    const int* __restrict__ s3, const int* __restrict__ d3,
    const int* __restrict__ histG, int* __restrict__ bins,
    int E1, int E12, int ET, int chunk, int NBall, int B2, int B3) {
  __shared__ int stage[CHUNK];
  __shared__ int cnt[NBCAP];
  __shared__ int cur[NBCAP];
  const int tid = threadIdx.x;
  const int k = blockIdx.x;
  for (int i = tid; i < NBall; i += 1024) cnt[i] = 0;
  __syncthreads();
  const int lo = k * chunk, hi = min(ET, lo + chunk);
  // pass 1: local histogram (dst only)
  for (int e = lo + tid; e < hi; e += 1024) {
    int l, ee;
    if (e < E1) { l = 0; ee = e; }
    else if (e < E12) { l = 1; ee = e - E1; }
    else { l = 2; ee = e - E12; }
    const int* dp = (l == 0) ? d1 : (l == 1) ? d2 : d3;
    int base = (l == 0) ? 0 : (l == 1) ? B2 : B3;
    atomicAdd(&cnt[base + (dp[ee] >> 8)], 1);
  }
  __syncthreads();
  // scan cnt -> cur (exclusive): one bucket per thread (NBCAP <= 1024), scratch in stage[]
  int sum = (tid < NBall) ? cnt[tid] : 0;
  stage[tid] = sum;
  __syncthreads();
  for (int off = 1; off < 1024; off <<= 1) {
    int t = (tid >= off) ? stage[tid - off] : 0;
    __syncthreads();
    stage[tid] += t;
    __syncthreads();
  }
  if (tid < NBall) cur[tid] = stage[tid] - sum;
  __syncthreads();  // stage reads done before pass-2 reuse
  // pass 2: stage packed entries at block-local positions
  for (int e = lo + tid; e < hi; e += 1024) {
    int l, ee;
    if (e < E1) { l = 0; ee = e; }
    else if (e < E12) { l = 1; ee = e - E1; }
    else { l = 2; ee = e - E12; }
    const int* sp = (l == 0) ? s1 : (l == 1) ? s2 : s3;
    const int* dp = (l == 0) ? d1 : (l == 1) ? d2 : d3;
    int base = (l == 0) ? 0 : (l == 1) ? B2 : B3;
    int d = dp[ee];
    int p = atomicAdd(&cur[base + (d >> 8)], 1);  // LDS atomic, block-local position
    stage[p] = sp[ee] | ((d & 255) << 18);
  }
  __syncthreads();
  // flush: wave-per-bucket round-robin; each segment contiguous in LDS and global
  const int wave = tid >> 6, lane = tid & 63;
  for (int b = wave; b < NBall; b += 16) {
    int cb = cnt[b];
    int lbase = cur[b] - cb;
    int gbase = histG[b * NBLK + k];
    for (int t = lane; t < cb; t += 64) bins[gbase + t] = stage[lbase + t];
  }
}

template <int CHUNK, int NBCAP>
__global__ __launch_bounds__(1024) void part_scatter4_staged(
    const int* __restrict__ src, const int* __restrict__ dst,
    const int* __restrict__ histG, int* __restrict__ bins,
    int E, int chunk, int NBall) {
  __shared__ int stage[CHUNK];
  __shared__ int cnt[NBCAP];
  __shared__ int cur[NBCAP];
  const int tid = threadIdx.x;
  const int k = blockIdx.x;
  for (int i = tid; i < NBall; i += 1024) cnt[i] = 0;
  __syncthreads();
  const int lo = k * chunk, hi = min(E, lo + chunk);
  for (int e = lo + tid; e < hi; e += 1024) atomicAdd(&cnt[dst[e] >> 8], 1);
  __syncthreads();
  int sum = (tid < NBall) ? cnt[tid] : 0;
  stage[tid] = sum;
  __syncthreads();
  for (int off = 1; off < 1024; off <<= 1) {
    int t = (tid >= off) ? stage[tid - off] : 0;
    __syncthreads();
    stage[tid] += t;
    __syncthreads();
  }
  if (tid < NBall) cur[tid] = stage[tid] - sum;
  __syncthreads();
  for (int e = lo + tid; e < hi; e += 1024) {
    int d = dst[e];
    int p = atomicAdd(&cur[d >> 8], 1);
    stage[p] = src[e] | ((d & 255) << 18);
  }
  __syncthreads();
  const int wave = tid >> 6, lane = tid & 63;
  for (int b = wave; b < NBall; b += 16) {
    int cb = cnt[b];
    int lbase = cur[b] - cb;
    int gbase = histG[b * NBLK + k];
    for (int t = lane; t < cb; t += 64) bins[gbase + t] = stage[lbase + t];
  }
}

// ---------------- in-place csrify (uniform 256-node buckets, rv[24]) ----------------
__global__ __launch_bounds__(256) void csrifyA_kernel(
    int* __restrict__ bins, const int* __restrict__ boffs,
    int* __restrict__ no1, int* __restrict__ no2, int* __restrict__ no3,
    float* __restrict__ dv1, float* __restrict__ dv2, float* __restrict__ dv3,
    int n1, int n2, int n3, int NB1, int NB2, int NB3) {
  __shared__ int cnt[256];
  __shared__ int scanv[256];
  __shared__ int cur[256];
  const int bb = blockIdx.x;
  const int tid = threadIdx.x;
  int lb, nl, nbl;
  int* noffs;
  float* dinv;
  if (bb < NB1) { lb = bb; nl = n1; nbl = NB1; noffs = no1; dinv = dv1; }
  else if (bb < NB1 + NB2) { lb = bb - NB1; nl = n2; nbl = NB2; noffs = no2; dinv = dv2; }
  else { lb = bb - NB1 - NB2; nl = n3; nbl = NB3; noffs = no3; dinv = dv3; }
  cnt[tid] = 0;
  __syncthreads();
  const int start = boffs[bb], end = boffs[bb + 1];
  int rv[24];  // bucket <= 6144 edges (mean ~4082, +32 sigma headroom)
#pragma unroll
  for (int kk = 0; kk < 24; kk++) {
    int e = start + tid + kk * 256;
    rv[kk] = (e < end) ? bins[e] : -1;
    if (rv[kk] != -1) atomicAdd(&cnt[rv[kk] >> 18], 1);
  }
  __syncthreads();
  scanv[tid] = cnt[tid];
  __syncthreads();
  for (int off = 1; off < 256; off <<= 1) {
    int t = (tid >= off) ? scanv[tid - off] : 0;
    __syncthreads();
    scanv[tid] += t;
    __syncthreads();
  }
  int excl = scanv[tid] - cnt[tid];
  cur[tid] = excl;
  int node = lb * 256 + tid;
  if (node < nl) {
    noffs[node] = start + excl;
    dinv[node] = rsqrtf((float)cnt[tid] + 1.0f);  // +1 = self loop
  }
  if (lb == nbl - 1 && tid == 0) noffs[nl] = end;
  __syncthreads();
#pragma unroll
  for (int kk = 0; kk < 24; kk++) {
    if (rv[kk] != -1) {
      int dl = rv[kk] >> 18;
      int pos = start + atomicAdd(&cur[dl], 1);
      bins[pos] = rv[kk] & 0x3FFFF;  // in-place: all reads done before first write
    }
  }
}

__global__ __launch_bounds__(256) void csrify4_kernel(int* __restrict__ bins,
                                                      const int* __restrict__ boffs,
                                                      int* __restrict__ noffs,
                                                      float* __restrict__ dinv,
                                                      int n, int NB) {
  __shared__ int cnt[256];
  __shared__ int scanv[256];
  __shared__ int cur[256];
  const int bb = blockIdx.x;
  const int tid = threadIdx.x;
  cnt[tid] = 0;
  __syncthreads();
  const int start = boffs[bb], end = boffs[bb + 1];
  int rv[24];
#pragma unroll
  for (int kk = 0; kk < 24; kk++) {
    int e = start + tid + kk * 256;
    rv[kk] = (e < end) ? bins[e] : -1;
    if (rv[kk] != -1) atomicAdd(&cnt[rv[kk] >> 18], 1);
  }
  __syncthreads();
  scanv[tid] = cnt[tid];
  __syncthreads();
  for (int off = 1; off < 256; off <<= 1) {
    int t = (tid >= off) ? scanv[tid - off] : 0;
    __syncthreads();
    scanv[tid] += t;
    __syncthreads();
  }
  int excl = scanv[tid] - cnt[tid];
  cur[tid] = excl;
  int node = bb * 256 + tid;
  if (node < n) {
    noffs[node] = start + excl;
    dinv[node] = rsqrtf((float)cnt[tid] + 1.0f);
  }
  if (bb == NB - 1 && tid == 0) noffs[n] = end;
  __syncthreads();
#pragma unroll
  for (int kk = 0; kk < 24; kk++) {
    if (rv[kk] != -1) {
      int dl = rv[kk] >> 18;
      int pos = start + atomicAdd(&cur[dl], 1);
      bins[pos] = rv[kk] & 0x3FFFF;
    }
  }
}

// ---------------- float4 per-node gather (unchanged, proven) ----------------
template <int C, int HSHIFT>
__global__ __launch_bounds__(256) void node_gather4_kernel(const int* __restrict__ csr,
                                                           const int* __restrict__ noffs,
                                                           const float* __restrict__ dinv,
                                                           const float* __restrict__ h,
                                                           const float* __restrict__ b,
                                                           float* __restrict__ out, int n) {
  constexpr int LPN = C / 4;
  constexpr int NPB = 256 / LPN;
  const int node = blockIdx.x * NPB + threadIdx.x / LPN;
  const int c4 = (threadIdx.x % LPN) * 4;
  if (node >= n) return;
  const float4* __restrict__ h4 = reinterpret_cast<const float4*>(h);
  const int start = noffs[node];
  const int end = noffs[node + 1];
  const float dd = dinv[node];
  float4 sv = h4[(((long)(node >> HSHIFT)) * C + c4) >> 2];  // self loop
  float4 acc;
  acc.x = dd * sv.x; acc.y = dd * sv.y; acc.z = dd * sv.z; acc.w = dd * sv.w;
  int j = start;
  for (; j + 1 < end; j += 2) {
    int s0 = csr[j], s1 = csr[j + 1];
    float w0 = dinv[s0], w1 = dinv[s1];
    float4 v0 = h4[(((long)(s0 >> HSHIFT)) * C + c4) >> 2];
    float4 v1 = h4[(((long)(s1 >> HSHIFT)) * C + c4) >> 2];
    acc.x = fmaf(w0, v0.x, acc.x); acc.y = fmaf(w0, v0.y, acc.y);
    acc.z = fmaf(w0, v0.z, acc.z); acc.w = fmaf(w0, v0.w, acc.w);
    acc.x = fmaf(w1, v1.x, acc.x); acc.y = fmaf(w1, v1.y, acc.y);
    acc.z = fmaf(w1, v1.z, acc.z); acc.w = fmaf(w1, v1.w, acc.w);
  }
  if (j < end) {
    int s0 = csr[j];
    float w0 = dinv[s0];
    float4 v0 = h4[(((long)(s0 >> HSHIFT)) * C + c4) >> 2];
    acc.x = fmaf(w0, v0.x, acc.x); acc.y = fmaf(w0, v0.y, acc.y);
    acc.z = fmaf(w0, v0.z, acc.z); acc.w = fmaf(w0, v0.w, acc.w);
  }
  const float4 bb4 = *reinterpret_cast<const float4*>(b + c4);
  float4 o;
  o.x = fmaf(dd, acc.x, bb4.x); o.y = fmaf(dd, acc.y, bb4.y);
  o.z = fmaf(dd, acc.z, bb4.z); o.w = fmaf(dd, acc.w, bb4.w);
  *reinterpret_cast<float4*>(out + (long)node * C + c4) = o;
}

// ---------------- gemm_mn: MRx8 microtile, dbuf + reg prefetch, 1 sync/tile ----------
// 256 threads: TX = BN/8 col-groups x TY = 256/TX row-groups; MR = BM/TY in {2, 4}.
// acc <= 32 regs; __launch_bounds__(256,4) caps VGPR at 128 -> 16 waves/CU.
// xs padded +4: staging writes 2-way (free); b-frag reads contiguous 16B/lane; a-frag
// reads broadcast. Tiles sized so every layer launches >= 782 blocks (>= 3 blocks/CU).
template <int CIN, int COUT, int BM, int BN, int MR, bool RELU>
__global__ __launch_bounds__(256, 4) void gemm_mn(const float* __restrict__ x,
                                                  const float* __restrict__ W,
                                                  float* __restrict__ h, int n) {
  constexpr int KT = 16;
  constexpr int TX = BN / 8;
  constexpr int TY = 256 / TX;
  static_assert(TY * MR == BM, "thread grid must tile BM");
  constexpr int ATOT = BM * (KT / 4);           // total A float4s per tile
  constexpr int BTOT = KT * (BN / 4);           // total B float4s per tile
  constexpr int AF4 = (ATOT + 255) / 256;
  constexpr int BF4 = BTOT / 256;
  static_assert(BTOT % 256 == 0, "B staging must be exact");
  constexpr int NT = CIN / KT;

  __shared__ float xs[2][KT][BM + 4];  // k-major (transposed x tile), +4 pad
  __shared__ float ws[2][KT][BN];

  const int tid = threadIdx.x;
  const int tx = tid % TX;
  const int ty = tid / TX;
  const int rowbase = blockIdx.x * BM;
  const int colbase = blockIdx.y * BN;

  float4 pa[AF4];
  float4 pb[BF4];

  auto stage_load = [&](int t) {
    const int k0 = t * KT;
    if constexpr (ATOT >= 256) {
#pragma unroll
      for (int u = 0; u < AF4; ++u) {
        const int i = u * 256 + tid;
        const int r = i >> 2, kq = i & 3;
        const int gr = rowbase + r;
        float4 v = make_float4(0.f, 0.f, 0.f, 0.f);
        if (gr < n) v = *reinterpret_cast<const float4*>(&x[(long)gr * CIN + k0 + kq * 4]);
        if (RELU) {
          v.x = fmaxf(v.x, 0.f); v.y = fmaxf(v.y, 0.f);
          v.z = fmaxf(v.z, 0.f); v.w = fmaxf(v.w, 0.f);
        }
        pa[u] = v;
      }
    } else {
      if (tid < ATOT) {
        const int r = tid >> 2, kq = tid & 3;
        const int gr = rowbase + r;
        float4 v = make_float4(0.f, 0.f, 0.f, 0.f);
        if (gr < n) v = *reinterpret_cast<const float4*>(&x[(long)gr * CIN + k0 + kq * 4]);
        if (RELU) {
          v.x = fmaxf(v.x, 0.f); v.y = fmaxf(v.y, 0.f);
          v.z = fmaxf(v.z, 0.f); v.w = fmaxf(v.w, 0.f);
        }
        pa[0] = v;
      }
    }
#pragma unroll
    for (int u = 0; u < BF4; ++u) {
      const int i = u * 256 + tid;
      const int k = i / (BN / 4), cq = i % (BN / 4);
      pb[u] = *reinterpret_cast<const float4*>(&W[(long)(k0 + k) * COUT + colbase + cq * 4]);
    }
  };
  auto stage_write = [&](int buf) {
    if constexpr (ATOT >= 256) {
#pragma unroll
      for (int u = 0; u < AF4; ++u) {
        const int i = u * 256 + tid;
        const int r = i >> 2, kq = i & 3;
        xs[buf][kq * 4 + 0][r] = pa[u].x;
        xs[buf][kq * 4 + 1][r] = pa[u].y;
        xs[buf][kq * 4 + 2][r] = pa[u].z;
        xs[buf][kq * 4 + 3][r] = pa[u].w;
      }
    } else {
      if (tid < ATOT) {
        const int r = tid >> 2, kq = tid & 3;
        xs[buf][kq * 4 + 0][r] = pa[0].x;
        xs[buf][kq * 4 + 1][r] = pa[0].y;
        xs[buf][kq * 4 + 2][r] = pa[0].z;
        xs[buf][kq * 4 + 3][r] = pa[0].w;
      }
    }
#pragma unroll
    for (int u = 0; u < BF4; ++u) {
      const int i = u * 256 + tid;
      const int k = i / (BN / 4), cq = i % (BN / 4);
      *reinterpret_cast<float4*>(&ws[buf][k][cq * 4]) = pb[u];
    }
  };

  float acc[MR][8];
#pragma unroll
  for (int i = 0; i < MR; ++i)
#pragma unroll
    for (int j = 0; j < 8; ++j) acc[i][j] = 0.f;

  stage_load(0);
  stage_write(0);
  __syncthreads();

  for (int t = 0; t < NT; ++t) {
    const int cur = t & 1;
    if (t + 1 < NT) stage_load(t + 1);  // issue early: HBM latency hides under compute
#pragma unroll
    for (int k = 0; k < KT; ++k) {
      const float4 w0 = *reinterpret_cast<const float4*>(&ws[cur][k][tx * 4]);
      const float4 w1 = *reinterpret_cast<const float4*>(&ws[cur][k][BN / 2 + tx * 4]);
      float wr[8] = {w0.x, w0.y, w0.z, w0.w, w1.x, w1.y, w1.z, w1.w};
      float ar[MR];
      if constexpr (MR == 4) {
        const float4 a0 = *reinterpret_cast<const float4*>(&xs[cur][k][ty * 4]);
        ar[0] = a0.x; ar[1] = a0.y; ar[2] = a0.z; ar[3] = a0.w;
      } else {
        const float2 a0 = *reinterpret_cast<const float2*>(&xs[cur][k][ty * 2]);
        ar[0] = a0.x; ar[1] = a0.y;
      }
#pragma unroll
      for (int i = 0; i < MR; ++i)
#pragma unroll
        for (int j = 0; j < 8; ++j) acc[i][j] = fmaf(ar[i], wr[j], acc[i][j]);
    }
    if (t + 1 < NT) stage_write(cur ^ 1);  // target buf last read at iter t-1 (barrier-safe)
    __syncthreads();
  }

#pragma unroll
  for (int i = 0; i < MR; ++i) {
    const int gr = rowbase + ty * MR + i;
    if (gr < n) {
      float4 o0 = make_float4(acc[i][0], acc[i][1], acc[i][2], acc[i][3]);
      float4 o1 = make_float4(acc[i][4], acc[i][5], acc[i][6], acc[i][7]);
      *reinterpret_cast<float4*>(&h[(long)gr * COUT + colbase + tx * 4]) = o0;
      *reinterpret_cast<float4*>(&h[(long)gr * COUT + colbase + BN / 2 + tx * 4]) = o1;
    }
  }
}

template <int CIN, int COUT, int TM, bool RELU>
__global__ __launch_bounds__(256) void gemm_small(const float* __restrict__ x,
                                                  const float* __restrict__ W,
                                                  float* __restrict__ h, int n) {
  __shared__ float xs[TM][CIN + 1];
  const int tid = threadIdx.x;
  const int base = blockIdx.x * TM;
  for (int idx = tid; idx < TM * CIN; idx += 256) {
    int m = idx / CIN, k = idx - m * CIN;
    int r = base + m;
    float v = 0.f;
    if (r < n) {
      v = x[(long)r * CIN + k];
      if (RELU) v = fmaxf(v, 0.f);
    }
    xs[m][k] = v;
  }
  __syncthreads();
  constexpr int GROUPS = 256 / COUT;
  constexpr int ACC = TM / GROUPS;
  const int c = tid % COUT;
  const int mg = tid / COUT;
  float acc[ACC];
#pragma unroll
  for (int a = 0; a < ACC; a++) acc[a] = 0.f;
#pragma unroll 8
  for (int k = 0; k < CIN; k++) {
    float wk = W[k * COUT + c];
#pragma unroll
    for (int a = 0; a < ACC; a++) acc[a] = fmaf(xs[mg + a * GROUPS][k], wk, acc[a]);
  }
#pragma unroll
  for (int a = 0; a < ACC; a++) {
    int r = base + mg + a * GROUPS;
    if (r < n) h[(long)r * COUT + c] = acc[a];
  }
}

extern "C" void kernel_launch(void* const* d_in, const int* in_sizes, int n_in,
                              void* d_out, int out_size, void* d_ws, size_t ws_size,
                              hipStream_t stream) {
  const float* z  = (const float*)d_in[0];
  const int* ei   = (const int*)d_in[1];
  const int* ps2  = (const int*)d_in[2];
  const int* ps1  = (const int*)d_in[3];
  const int* ps0  = (const int*)d_in[4];
  const float* W1 = (const float*)d_in[5];  const float* b1 = (const float*)d_in[6];
  const float* W2 = (const float*)d_in[7];  const float* b2 = (const float*)d_in[8];
  const float* W3 = (const float*)d_in[9];  const float* b3 = (const float*)d_in[10];
  const float* W4 = (const float*)d_in[11]; const float* b4 = (const float*)d_in[12];
  float* out = (float*)d_out;

  const int N  = in_sizes[0] / 256;  // 25000
  const int E1 = in_sizes[1] / 2;    // 400000
  const int E2 = in_sizes[2] / 2;    // 800000
  const int E3 = in_sizes[3] / 2;    // 1600000
  const int E4 = in_sizes[4] / 2;    // 3200000
  const int n1 = N, n2 = 2 * N, n3 = 4 * N, n4 = 8 * N;
  const int E12 = E1 + E2, ETA = E1 + E2 + E3;
  // uniform 256-node buckets
  const int NB1 = cdiv(n1, 256);     // 98
  const int NB2 = cdiv(n2, 256);     // 196
  const int NB3 = cdiv(n3, 256);     // 391
  const int NB4 = cdiv(n4, 256);     // 782
  const int NBA = NB1 + NB2 + NB3;   // 685
  const int B2b = NB1, B3b = NB1 + NB2;
  const int NTA = NBA * NBLK;        // 350,720
  const int nbsA = cdiv(NTA, 256);   // 1370
  const int nbsA2 = cdiv(nbsA, 256); // 6
  const int NTB = NB4 * NBLK;        // 400,384
  const int nbsB = cdiv(NTB, 256);   // 1564
  const int nbsB2 = cdiv(nbsB, 256); // 7
  const int chunk3 = cdiv(ETA, NBLK);  // 5469
  const int chunk4 = cdiv(E4, NBLK);   // 6250

  // ---- workspace map (same F-region scheme as R8-R10, proven) ----
  float* F = (float*)d_ws;
  float* h1 = F;
  float* out1 = F + 6400000;
  float* h2 = F;
  int* binsB = (int*)(F + 3200000);  // csr4; overlays dead h1 upper half (post-gather1)
  float* out2 = F + 6400000;
  float* h3 = F;
  float* out3 = F + 6400000;
  float* h4 = F;

  int* P = (int*)(F + 12800000);
  int* binsA = P;                         // ETA ints (csr123 after in-place csrify)
  int* no1 = P + ETA;
  int* no2 = no1 + (n1 + 1);
  int* no3 = no2 + (n2 + 1);
  int* no4 = no3 + (n3 + 1);
  float* dv1 = (float*)(no4 + (n4 + 1));
  float* dv2 = dv1 + n1;
  float* dv3 = dv2 + n2;
  float* dv4 = dv3 + n3;
  int* S = (int*)(dv4 + n4);
  int* histA = S;                         // NTA
  int* psumA = histA + NTA;               // 2048 (need nbsA=1370)
  int* psumA2 = psumA + 2048;             // 64
  int* boffsA = psumA2 + 64;              // NBA+1
  int* histB = boffsA + (NBA + 1);        // NTB
  int* psumB = histB + NTB;               // 2048 (need nbsB=1564)
  int* psumB2 = psumB + 2048;             // 64
  int* boffsB = psumB2 + 64;              // NB4+1

  // ---------------- partition layers 1-3 (batched chain, staged scatter) ----------------
  part_hist3_kernel<<<NBLK, 1024, 0, stream>>>(ei + E1, ps2 + E2, ps1 + E3, histA,
                                               E1, E12, ETA, chunk3, NBA, B2b, B3b);
  scan_block_kernel<<<nbsA, 256, 0, stream>>>(histA, histA, psumA, NTA);
  scan_block_kernel<<<nbsA2, 256, 0, stream>>>(psumA, psumA, psumA2, nbsA);
  scan_psum_kernel<<<1, 1024, 0, stream>>>(psumA2, nbsA2);
  scan_add_kernel<<<nbsA2, 256, 0, stream>>>(psumA, psumA2, nbsA);
  scan_add_kernel<<<nbsA, 256, 0, stream>>>(histA, psumA, NTA);
  extract_offs_kernel<<<cdiv(NBA + 1, 256), 256, 0, stream>>>(histA, boffsA, NBA, ETA);
  part_scatter3_staged<5472, 688><<<NBLK, 1024, 0, stream>>>(
      ei, ei + E1, ps2, ps2 + E2, ps1, ps1 + E3, histA, binsA,
      E1, E12, ETA, chunk3, NBA, B2b, B3b);
  csrifyA_kernel<<<NBA, 256, 0, stream>>>(binsA, boffsA, no1, no2, no3,
                                          dv1, dv2, dv3, n1, n2, n3, NB1, NB2, NB3);

  // layer-4 hist+scan upfront (touches only S region)
  part_hist4_kernel<<<NBLK, 1024, 0, stream>>>(ps0 + E4, histB, E4, chunk4, NB4);
  scan_block_kernel<<<nbsB, 256, 0, stream>>>(histB, histB, psumB, NTB);
  scan_block_kernel<<<nbsB2, 256, 0, stream>>>(psumB, psumB, psumB2, nbsB);
  scan_psum_kernel<<<1, 1024, 0, stream>>>(psumB2, nbsB2);
  scan_add_kernel<<<nbsB2, 256, 0, stream>>>(psumB, psumB2, nbsB);
  scan_add_kernel<<<nbsB, 256, 0, stream>>>(histB, psumB, NTB);
  extract_offs_kernel<<<cdiv(NB4 + 1, 256), 256, 0, stream>>>(histB, boffsB, NB4, E4);

  // ---------------- Layer 1: h1 (Nx256), out1 ----------------
  gemm_mn<256, 256, 64, 128, 4, false><<<dim3(cdiv(n1, 64), 2), 256, 0, stream>>>(z, W1, h1, n1);
  node_gather4_kernel<256, 0><<<cdiv(n1, 4), 256, 0, stream>>>(binsA, no1, dv1, h1, b1, out1, n1);

  // layer-4 scatter+csrify (binsB overlays dead h1 upper half; after gather1)
  part_scatter4_staged<6256, 784><<<NBLK, 1024, 0, stream>>>(ps0, ps0 + E4, histB, binsB,
                                                             E4, chunk4, NB4);
  csrify4_kernel<<<NB4, 256, 0, stream>>>(binsB, boffsB, no4, dv4, n4, NB4);

  // ---------------- Layer 2: h2 (Nx128), out2 (2N x 128) ----------------
  gemm_mn<256, 128, 32, 128, 2, true><<<dim3(cdiv(N, 32), 1), 256, 0, stream>>>(out1, W2, h2, N);
  node_gather4_kernel<128, 1><<<cdiv(n2, 8), 256, 0, stream>>>(binsA, no2, dv2, h2, b2, out2, n2);

  // ---------------- Layer 3: h3 (2N x 64), out3 (4N x 64) ----------------
  gemm_mn<128, 64, 64, 64, 2, true><<<dim3(cdiv(2 * N, 64), 1), 256, 0, stream>>>(out2, W3, h3, 2 * N);
  node_gather4_kernel<64, 1><<<cdiv(n3, 16), 256, 0, stream>>>(binsA, no3, dv3, h3, b3, out3, n3);

  // ---------------- Layer 4: h4 (4N x 8), out4 = d_out (8N x 8) ----------------
  gemm_small<64, 8, 32, true><<<cdiv(4 * N, 32), 256, 0, stream>>>(out3, W4, h4, 4 * N);
  node_gather4_kernel<8, 1><<<cdiv(n4, 128), 256, 0, stream>>>(binsB, no4, dv4, h4, b4, out, n4);
}

// Round 3
// 600.650 us; speedup vs baseline: 1.7994x; 1.7994x over previous
//
#include <hip/hip_runtime.h>

// GCN decoder: batched deterministic radix partition (LDS-staged scatter, 512x1024) ->
// in-place per-node CSR -> float4 register gather; fp32 GEMMs.
// upsample2 identity: h = upsample2(x) @ W has h[2i]==h[2i+1] -> compute h on the
// pre-upsample node set, index with (node >> HSHIFT).
// R13 post-mortem: __launch_bounds__(256,4) forced VGPR=64 -> massive scratch spill
// (L2 gemm FETCH 537MB WRITE 950MB, 373us). NEVER cap min-waves on reg-hungry kernels.
// R14: gemm_mn MR=4 only, NO register cap (R1's proven dbuf structure that improved
// L2/L3); L1 = <256,256,64,128,4> grid 782. acc 32 regs -> expect ~120 VGPR,
// 3-4 waves/SIMD. Predicted L1 ~40us, total ~575us.

static inline int cdiv(long a, int b) { return (int)((a + b - 1) / b); }
static constexpr int NBLK = 512;  // partition chunks / histogram columns

// ---------------- hist: per-chunk histogram (bucket-major table) ----------------
__global__ __launch_bounds__(1024) void part_hist3_kernel(
    const int* __restrict__ d1, const int* __restrict__ d2, const int* __restrict__ d3,
    int* __restrict__ histG, int E1, int E12, int ET, int chunk, int NBall, int B2, int B3) {
  __shared__ int hist[688];
  for (int i = threadIdx.x; i < NBall; i += 1024) hist[i] = 0;
  __syncthreads();
  const int k = blockIdx.x;
  const int lo = k * chunk, hi = min(ET, lo + chunk);
  for (int e = lo + (int)threadIdx.x; e < hi; e += 1024) {
    int l, ee;
    if (e < E1) { l = 0; ee = e; }
    else if (e < E12) { l = 1; ee = e - E1; }
    else { l = 2; ee = e - E12; }
    const int* dp = (l == 0) ? d1 : (l == 1) ? d2 : d3;
    int base = (l == 0) ? 0 : (l == 1) ? B2 : B3;
    atomicAdd(&hist[base + (dp[ee] >> 8)], 1);
  }
  __syncthreads();
  for (int i = threadIdx.x; i < NBall; i += 1024) histG[i * NBLK + k] = hist[i];
}

__global__ __launch_bounds__(1024) void part_hist4_kernel(const int* __restrict__ dst,
                                                          int* __restrict__ histG,
                                                          int E, int chunk, int NBall) {
  __shared__ int hist[784];
  for (int i = threadIdx.x; i < NBall; i += 1024) hist[i] = 0;
  __syncthreads();
  const int k = blockIdx.x;
  const int lo = k * chunk, hi = min(E, lo + chunk);
  for (int e = lo + (int)threadIdx.x; e < hi; e += 1024)
    atomicAdd(&hist[dst[e] >> 8], 1);
  __syncthreads();
  for (int i = threadIdx.x; i < NBall; i += 1024) histG[i * NBLK + k] = hist[i];
}

// ---------------- scan primitives (in-place safe) ----------------
__global__ void scan_block_kernel(const int* __restrict__ in, int* __restrict__ outv,
                                  int* __restrict__ psum, int n) {
  __shared__ int tmp[256];
  int i = blockIdx.x * 256 + threadIdx.x;
  int v = (i < n) ? in[i] : 0;
  tmp[threadIdx.x] = v;
  __syncthreads();
  for (int off = 1; off < 256; off <<= 1) {
    int t = (threadIdx.x >= off) ? tmp[threadIdx.x - off] : 0;
    __syncthreads();
    tmp[threadIdx.x] += t;
    __syncthreads();
  }
  if (i < n) outv[i] = tmp[threadIdx.x] - v;
  if (threadIdx.x == 255) psum[blockIdx.x] = tmp[255];
}

__global__ __launch_bounds__(1024) void scan_psum_kernel(int* __restrict__ psum, int nb) {
  __shared__ int tmp[1024];
  int i = threadIdx.x;
  int v = (i < nb) ? psum[i] : 0;
  tmp[i] = v;
  __syncthreads();
  for (int off = 1; off < 1024; off <<= 1) {
    int t = (i >= off) ? tmp[i - off] : 0;
    __syncthreads();
    tmp[i] += t;
    __syncthreads();
  }
  if (i < nb) psum[i] = tmp[i] - v;
}

__global__ void scan_add_kernel(int* __restrict__ v, const int* __restrict__ psum, int n) {
  int i = blockIdx.x * 256 + threadIdx.x;
  if (i < n) v[i] += psum[blockIdx.x];
}

// boffs[g] = scanned histG[g*NBLK]; boffs[NBall] = Etot
__global__ void extract_offs_kernel(const int* __restrict__ histG, int* __restrict__ boffs,
                                    int NBall, int Etot) {
  int i = blockIdx.x * 256 + threadIdx.x;
  if (i < NBall) boffs[i] = histG[i * NBLK];
  if (i == NBall) boffs[NBall] = Etot;
}

// ---------------- LDS-staged scatter (1024 threads): stage chunk, flush contiguous ----------
template <int CHUNK, int NBCAP>
__global__ __launch_bounds__(1024) void part_scatter3_staged(
    const int* __restrict__ s1, const int* __restrict__ d1,
    const int* __restrict__ s2, const int* __restrict__ d2,
    const int* __restrict__ s3, const int* __restrict__ d3,
    const int* __restrict__ histG, int* __restrict__ bins,
    int E1, int E12, int ET, int chunk, int NBall, int B2, int B3) {
  __shared__ int stage[CHUNK];
  __shared__ int cnt[NBCAP];
  __shared__ int cur[NBCAP];
  const int tid = threadIdx.x;
  const int k = blockIdx.x;
  for (int i = tid; i < NBall; i += 1024) cnt[i] = 0;
  __syncthreads();
  const int lo = k * chunk, hi = min(ET, lo + chunk);
  // pass 1: local histogram (dst only)
  for (int e = lo + tid; e < hi; e += 1024) {
    int l, ee;
    if (e < E1) { l = 0; ee = e; }
    else if (e < E12) { l = 1; ee = e - E1; }
    else { l = 2; ee = e - E12; }
    const int* dp = (l == 0) ? d1 : (l == 1) ? d2 : d3;
    int base = (l == 0) ? 0 : (l == 1) ? B2 : B3;
    atomicAdd(&cnt[base + (dp[ee] >> 8)], 1);
  }
  __syncthreads();
  // scan cnt -> cur (exclusive): one bucket per thread (NBCAP <= 1024), scratch in stage[]
  int sum = (tid < NBall) ? cnt[tid] : 0;
  stage[tid] = sum;
  __syncthreads();
  for (int off = 1; off < 1024; off <<= 1) {
    int t = (tid >= off) ? stage[tid - off] : 0;
    __syncthreads();
    stage[tid] += t;
    __syncthreads();
  }
  if (tid < NBall) cur[tid] = stage[tid] - sum;
  __syncthreads();  // stage reads done before pass-2 reuse
  // pass 2: stage packed entries at block-local positions
  for (int e = lo + tid; e < hi; e += 1024) {
    int l, ee;
    if (e < E1) { l = 0; ee = e; }
    else if (e < E12) { l = 1; ee = e - E1; }
    else { l = 2; ee = e - E12; }
    const int* sp = (l == 0) ? s1 : (l == 1) ? s2 : s3;
    const int* dp = (l == 0) ? d1 : (l == 1) ? d2 : d3;
    int base = (l == 0) ? 0 : (l == 1) ? B2 : B3;
    int d = dp[ee];
    int p = atomicAdd(&cur[base + (d >> 8)], 1);  // LDS atomic, block-local position
    stage[p] = sp[ee] | ((d & 255) << 18);
  }
  __syncthreads();
  // flush: wave-per-bucket round-robin; each segment contiguous in LDS and global
  const int wave = tid >> 6, lane = tid & 63;
  for (int b = wave; b < NBall; b += 16) {
    int cb = cnt[b];
    int lbase = cur[b] - cb;
    int gbase = histG[b * NBLK + k];
    for (int t = lane; t < cb; t += 64) bins[gbase + t] = stage[lbase + t];
  }
}

template <int CHUNK, int NBCAP>
__global__ __launch_bounds__(1024) void part_scatter4_staged(
    const int* __restrict__ src, const int* __restrict__ dst,
    const int* __restrict__ histG, int* __restrict__ bins,
    int E, int chunk, int NBall) {
  __shared__ int stage[CHUNK];
  __shared__ int cnt[NBCAP];
  __shared__ int cur[NBCAP];
  const int tid = threadIdx.x;
  const int k = blockIdx.x;
  for (int i = tid; i < NBall; i += 1024) cnt[i] = 0;
  __syncthreads();
  const int lo = k * chunk, hi = min(E, lo + chunk);
  for (int e = lo + tid; e < hi; e += 1024) atomicAdd(&cnt[dst[e] >> 8], 1);
  __syncthreads();
  int sum = (tid < NBall) ? cnt[tid] : 0;
  stage[tid] = sum;
  __syncthreads();
  for (int off = 1; off < 1024; off <<= 1) {
    int t = (tid >= off) ? stage[tid - off] : 0;
    __syncthreads();
    stage[tid] += t;
    __syncthreads();
  }
  if (tid < NBall) cur[tid] = stage[tid] - sum;
  __syncthreads();
  for (int e = lo + tid; e < hi; e += 1024) {
    int d = dst[e];
    int p = atomicAdd(&cur[d >> 8], 1);
    stage[p] = src[e] | ((d & 255) << 18);
  }
  __syncthreads();
  const int wave = tid >> 6, lane = tid & 63;
  for (int b = wave; b < NBall; b += 16) {
    int cb = cnt[b];
    int lbase = cur[b] - cb;
    int gbase = histG[b * NBLK + k];
    for (int t = lane; t < cb; t += 64) bins[gbase + t] = stage[lbase + t];
  }
}

// ---------------- in-place csrify (uniform 256-node buckets, rv[24]) ----------------
__global__ __launch_bounds__(256) void csrifyA_kernel(
    int* __restrict__ bins, const int* __restrict__ boffs,
    int* __restrict__ no1, int* __restrict__ no2, int* __restrict__ no3,
    float* __restrict__ dv1, float* __restrict__ dv2, float* __restrict__ dv3,
    int n1, int n2, int n3, int NB1, int NB2, int NB3) {
  __shared__ int cnt[256];
  __shared__ int scanv[256];
  __shared__ int cur[256];
  const int bb = blockIdx.x;
  const int tid = threadIdx.x;
  int lb, nl, nbl;
  int* noffs;
  float* dinv;
  if (bb < NB1) { lb = bb; nl = n1; nbl = NB1; noffs = no1; dinv = dv1; }
  else if (bb < NB1 + NB2) { lb = bb - NB1; nl = n2; nbl = NB2; noffs = no2; dinv = dv2; }
  else { lb = bb - NB1 - NB2; nl = n3; nbl = NB3; noffs = no3; dinv = dv3; }
  cnt[tid] = 0;
  __syncthreads();
  const int start = boffs[bb], end = boffs[bb + 1];
  int rv[24];  // bucket <= 6144 edges (mean ~4082, +32 sigma headroom)
#pragma unroll
  for (int kk = 0; kk < 24; kk++) {
    int e = start + tid + kk * 256;
    rv[kk] = (e < end) ? bins[e] : -1;
    if (rv[kk] != -1) atomicAdd(&cnt[rv[kk] >> 18], 1);
  }
  __syncthreads();
  scanv[tid] = cnt[tid];
  __syncthreads();
  for (int off = 1; off < 256; off <<= 1) {
    int t = (tid >= off) ? scanv[tid - off] : 0;
    __syncthreads();
    scanv[tid] += t;
    __syncthreads();
  }
  int excl = scanv[tid] - cnt[tid];
  cur[tid] = excl;
  int node = lb * 256 + tid;
  if (node < nl) {
    noffs[node] = start + excl;
    dinv[node] = rsqrtf((float)cnt[tid] + 1.0f);  // +1 = self loop
  }
  if (lb == nbl - 1 && tid == 0) noffs[nl] = end;
  __syncthreads();
#pragma unroll
  for (int kk = 0; kk < 24; kk++) {
    if (rv[kk] != -1) {
      int dl = rv[kk] >> 18;
      int pos = start + atomicAdd(&cur[dl], 1);
      bins[pos] = rv[kk] & 0x3FFFF;  // in-place: all reads done before first write
    }
  }
}

__global__ __launch_bounds__(256) void csrify4_kernel(int* __restrict__ bins,
                                                      const int* __restrict__ boffs,
                                                      int* __restrict__ noffs,
                                                      float* __restrict__ dinv,
                                                      int n, int NB) {
  __shared__ int cnt[256];
  __shared__ int scanv[256];
  __shared__ int cur[256];
  const int bb = blockIdx.x;
  const int tid = threadIdx.x;
  cnt[tid] = 0;
  __syncthreads();
  const int start = boffs[bb], end = boffs[bb + 1];
  int rv[24];
#pragma unroll
  for (int kk = 0; kk < 24; kk++) {
    int e = start + tid + kk * 256;
    rv[kk] = (e < end) ? bins[e] : -1;
    if (rv[kk] != -1) atomicAdd(&cnt[rv[kk] >> 18], 1);
  }
  __syncthreads();
  scanv[tid] = cnt[tid];
  __syncthreads();
  for (int off = 1; off < 256; off <<= 1) {
    int t = (tid >= off) ? scanv[tid - off] : 0;
    __syncthreads();
    scanv[tid] += t;
    __syncthreads();
  }
  int excl = scanv[tid] - cnt[tid];
  cur[tid] = excl;
  int node = bb * 256 + tid;
  if (node < n) {
    noffs[node] = start + excl;
    dinv[node] = rsqrtf((float)cnt[tid] + 1.0f);
  }
  if (bb == NB - 1 && tid == 0) noffs[n] = end;
  __syncthreads();
#pragma unroll
  for (int kk = 0; kk < 24; kk++) {
    if (rv[kk] != -1) {
      int dl = rv[kk] >> 18;
      int pos = start + atomicAdd(&cur[dl], 1);
      bins[pos] = rv[kk] & 0x3FFFF;
    }
  }
}

// ---------------- float4 per-node gather (unchanged, proven) ----------------
template <int C, int HSHIFT>
__global__ __launch_bounds__(256) void node_gather4_kernel(const int* __restrict__ csr,
                                                           const int* __restrict__ noffs,
                                                           const float* __restrict__ dinv,
                                                           const float* __restrict__ h,
                                                           const float* __restrict__ b,
                                                           float* __restrict__ out, int n) {
  constexpr int LPN = C / 4;
  constexpr int NPB = 256 / LPN;
  const int node = blockIdx.x * NPB + threadIdx.x / LPN;
  const int c4 = (threadIdx.x % LPN) * 4;
  if (node >= n) return;
  const float4* __restrict__ h4 = reinterpret_cast<const float4*>(h);
  const int start = noffs[node];
  const int end = noffs[node + 1];
  const float dd = dinv[node];
  float4 sv = h4[(((long)(node >> HSHIFT)) * C + c4) >> 2];  // self loop
  float4 acc;
  acc.x = dd * sv.x; acc.y = dd * sv.y; acc.z = dd * sv.z; acc.w = dd * sv.w;
  int j = start;
  for (; j + 1 < end; j += 2) {
    int s0 = csr[j], s1 = csr[j + 1];
    float w0 = dinv[s0], w1 = dinv[s1];
    float4 v0 = h4[(((long)(s0 >> HSHIFT)) * C + c4) >> 2];
    float4 v1 = h4[(((long)(s1 >> HSHIFT)) * C + c4) >> 2];
    acc.x = fmaf(w0, v0.x, acc.x); acc.y = fmaf(w0, v0.y, acc.y);
    acc.z = fmaf(w0, v0.z, acc.z); acc.w = fmaf(w0, v0.w, acc.w);
    acc.x = fmaf(w1, v1.x, acc.x); acc.y = fmaf(w1, v1.y, acc.y);
    acc.z = fmaf(w1, v1.z, acc.z); acc.w = fmaf(w1, v1.w, acc.w);
  }
  if (j < end) {
    int s0 = csr[j];
    float w0 = dinv[s0];
    float4 v0 = h4[(((long)(s0 >> HSHIFT)) * C + c4) >> 2];
    acc.x = fmaf(w0, v0.x, acc.x); acc.y = fmaf(w0, v0.y, acc.y);
    acc.z = fmaf(w0, v0.z, acc.z); acc.w = fmaf(w0, v0.w, acc.w);
  }
  const float4 bb4 = *reinterpret_cast<const float4*>(b + c4);
  float4 o;
  o.x = fmaf(dd, acc.x, bb4.x); o.y = fmaf(dd, acc.y, bb4.y);
  o.z = fmaf(dd, acc.z, bb4.z); o.w = fmaf(dd, acc.w, bb4.w);
  *reinterpret_cast<float4*>(out + (long)node * C + c4) = o;
}

// ---------------- gemm_mn: 4x8 microtile, dbuf + reg prefetch, 1 sync/tile ----------
// 256 threads: TX = BN/8 col-groups x TY = 256/TX row-groups; MR = BM/TY = 4.
// acc = 32 regs, NO register cap (R13 lesson: min-waves launch_bounds buys occupancy
// with scratch spills). xs padded +4; b-frag reads contiguous 16B/lane (split halves);
// a-frag reads broadcast. Every layer launches >= 391 blocks.
template <int CIN, int COUT, int BM, int BN, int MR, bool RELU>
__global__ __launch_bounds__(256) void gemm_mn(const float* __restrict__ x,
                                               const float* __restrict__ W,
                                               float* __restrict__ h, int n) {
  constexpr int KT = 16;
  constexpr int TX = BN / 8;
  constexpr int TY = 256 / TX;
  static_assert(TY * MR == BM, "thread grid must tile BM");
  constexpr int ATOT = BM * (KT / 4);           // total A float4s per tile
  constexpr int BTOT = KT * (BN / 4);           // total B float4s per tile
  static_assert(ATOT % 256 == 0, "A staging must be exact");
  static_assert(BTOT % 256 == 0, "B staging must be exact");
  constexpr int AF4 = ATOT / 256;
  constexpr int BF4 = BTOT / 256;
  constexpr int NT = CIN / KT;

  __shared__ float xs[2][KT][BM + 4];  // k-major (transposed x tile), +4 pad
  __shared__ float ws[2][KT][BN];

  const int tid = threadIdx.x;
  const int tx = tid % TX;
  const int ty = tid / TX;
  const int rowbase = blockIdx.x * BM;
  const int colbase = blockIdx.y * BN;

  float4 pa[AF4];
  float4 pb[BF4];

  auto stage_load = [&](int t) {
    const int k0 = t * KT;
#pragma unroll
    for (int u = 0; u < AF4; ++u) {
      const int i = u * 256 + tid;
      const int r = i >> 2, kq = i & 3;
      const int gr = rowbase + r;
      float4 v = make_float4(0.f, 0.f, 0.f, 0.f);
      if (gr < n) v = *reinterpret_cast<const float4*>(&x[(long)gr * CIN + k0 + kq * 4]);
      if (RELU) {
        v.x = fmaxf(v.x, 0.f); v.y = fmaxf(v.y, 0.f);
        v.z = fmaxf(v.z, 0.f); v.w = fmaxf(v.w, 0.f);
      }
      pa[u] = v;
    }
#pragma unroll
    for (int u = 0; u < BF4; ++u) {
      const int i = u * 256 + tid;
      const int k = i / (BN / 4), cq = i % (BN / 4);
      pb[u] = *reinterpret_cast<const float4*>(&W[(long)(k0 + k) * COUT + colbase + cq * 4]);
    }
  };
  auto stage_write = [&](int buf) {
#pragma unroll
    for (int u = 0; u < AF4; ++u) {
      const int i = u * 256 + tid;
      const int r = i >> 2, kq = i & 3;
      xs[buf][kq * 4 + 0][r] = pa[u].x;
      xs[buf][kq * 4 + 1][r] = pa[u].y;
      xs[buf][kq * 4 + 2][r] = pa[u].z;
      xs[buf][kq * 4 + 3][r] = pa[u].w;
    }
#pragma unroll
    for (int u = 0; u < BF4; ++u) {
      const int i = u * 256 + tid;
      const int k = i / (BN / 4), cq = i % (BN / 4);
      *reinterpret_cast<float4*>(&ws[buf][k][cq * 4]) = pb[u];
    }
  };

  float acc[MR][8];
#pragma unroll
  for (int i = 0; i < MR; ++i)
#pragma unroll
    for (int j = 0; j < 8; ++j) acc[i][j] = 0.f;

  stage_load(0);
  stage_write(0);
  __syncthreads();

  for (int t = 0; t < NT; ++t) {
    const int cur = t & 1;
    if (t + 1 < NT) stage_load(t + 1);  // issue early: HBM latency hides under compute
#pragma unroll
    for (int k = 0; k < KT; ++k) {
      const float4 w0 = *reinterpret_cast<const float4*>(&ws[cur][k][tx * 4]);
      const float4 w1 = *reinterpret_cast<const float4*>(&ws[cur][k][BN / 2 + tx * 4]);
      float wr[8] = {w0.x, w0.y, w0.z, w0.w, w1.x, w1.y, w1.z, w1.w};
      float ar[MR];
      {
        const float4 a0 = *reinterpret_cast<const float4*>(&xs[cur][k][ty * 4]);
        ar[0] = a0.x; ar[1] = a0.y; ar[2] = a0.z; ar[3] = a0.w;
      }
#pragma unroll
      for (int i = 0; i < MR; ++i)
#pragma unroll
        for (int j = 0; j < 8; ++j) acc[i][j] = fmaf(ar[i], wr[j], acc[i][j]);
    }
    if (t + 1 < NT) stage_write(cur ^ 1);  // target buf last read at iter t-1 (barrier-safe)
    __syncthreads();
  }

#pragma unroll
  for (int i = 0; i < MR; ++i) {
    const int gr = rowbase + ty * MR + i;
    if (gr < n) {
      float4 o0 = make_float4(acc[i][0], acc[i][1], acc[i][2], acc[i][3]);
      float4 o1 = make_float4(acc[i][4], acc[i][5], acc[i][6], acc[i][7]);
      *reinterpret_cast<float4*>(&h[(long)gr * COUT + colbase + tx * 4]) = o0;
      *reinterpret_cast<float4*>(&h[(long)gr * COUT + colbase + BN / 2 + tx * 4]) = o1;
    }
  }
}

template <int CIN, int COUT, int TM, bool RELU>
__global__ __launch_bounds__(256) void gemm_small(const float* __restrict__ x,
                                                  const float* __restrict__ W,
                                                  float* __restrict__ h, int n) {
  __shared__ float xs[TM][CIN + 1];
  const int tid = threadIdx.x;
  const int base = blockIdx.x * TM;
  for (int idx = tid; idx < TM * CIN; idx += 256) {
    int m = idx / CIN, k = idx - m * CIN;
    int r = base + m;
    float v = 0.f;
    if (r < n) {
      v = x[(long)r * CIN + k];
      if (RELU) v = fmaxf(v, 0.f);
    }
    xs[m][k] = v;
  }
  __syncthreads();
  constexpr int GROUPS = 256 / COUT;
  constexpr int ACC = TM / GROUPS;
  const int c = tid % COUT;
  const int mg = tid / COUT;
  float acc[ACC];
#pragma unroll
  for (int a = 0; a < ACC; a++) acc[a] = 0.f;
#pragma unroll 8
  for (int k = 0; k < CIN; k++) {
    float wk = W[k * COUT + c];
#pragma unroll
    for (int a = 0; a < ACC; a++) acc[a] = fmaf(xs[mg + a * GROUPS][k], wk, acc[a]);
  }
#pragma unroll
  for (int a = 0; a < ACC; a++) {
    int r = base + mg + a * GROUPS;
    if (r < n) h[(long)r * COUT + c] = acc[a];
  }
}

extern "C" void kernel_launch(void* const* d_in, const int* in_sizes, int n_in,
                              void* d_out, int out_size, void* d_ws, size_t ws_size,
                              hipStream_t stream) {
  const float* z  = (const float*)d_in[0];
  const int* ei   = (const int*)d_in[1];
  const int* ps2  = (const int*)d_in[2];
  const int* ps1  = (const int*)d_in[3];
  const int* ps0  = (const int*)d_in[4];
  const float* W1 = (const float*)d_in[5];  const float* b1 = (const float*)d_in[6];
  const float* W2 = (const float*)d_in[7];  const float* b2 = (const float*)d_in[8];
  const float* W3 = (const float*)d_in[9];  const float* b3 = (const float*)d_in[10];
  const float* W4 = (const float*)d_in[11]; const float* b4 = (const float*)d_in[12];
  float* out = (float*)d_out;

  const int N  = in_sizes[0] / 256;  // 25000
  const int E1 = in_sizes[1] / 2;    // 400000
  const int E2 = in_sizes[2] / 2;    // 800000
  const int E3 = in_sizes[3] / 2;    // 1600000
  const int E4 = in_sizes[4] / 2;    // 3200000
  const int n1 = N, n2 = 2 * N, n3 = 4 * N, n4 = 8 * N;
  const int E12 = E1 + E2, ETA = E1 + E2 + E3;
  // uniform 256-node buckets
  const int NB1 = cdiv(n1, 256);     // 98
  const int NB2 = cdiv(n2, 256);     // 196
  const int NB3 = cdiv(n3, 256);     // 391
  const int NB4 = cdiv(n4, 256);     // 782
  const int NBA = NB1 + NB2 + NB3;   // 685
  const int B2b = NB1, B3b = NB1 + NB2;
  const int NTA = NBA * NBLK;        // 350,720
  const int nbsA = cdiv(NTA, 256);   // 1370
  const int nbsA2 = cdiv(nbsA, 256); // 6
  const int NTB = NB4 * NBLK;        // 400,384
  const int nbsB = cdiv(NTB, 256);   // 1564
  const int nbsB2 = cdiv(nbsB, 256); // 7
  const int chunk3 = cdiv(ETA, NBLK);  // 5469
  const int chunk4 = cdiv(E4, NBLK);   // 6250

  // ---- workspace map (same F-region scheme as R8-R10, proven) ----
  float* F = (float*)d_ws;
  float* h1 = F;
  float* out1 = F + 6400000;
  float* h2 = F;
  int* binsB = (int*)(F + 3200000);  // csr4; overlays dead h1 upper half (post-gather1)
  float* out2 = F + 6400000;
  float* h3 = F;
  float* out3 = F + 6400000;
  float* h4 = F;

  int* P = (int*)(F + 12800000);
  int* binsA = P;                         // ETA ints (csr123 after in-place csrify)
  int* no1 = P + ETA;
  int* no2 = no1 + (n1 + 1);
  int* no3 = no2 + (n2 + 1);
  int* no4 = no3 + (n3 + 1);
  float* dv1 = (float*)(no4 + (n4 + 1));
  float* dv2 = dv1 + n1;
  float* dv3 = dv2 + n2;
  float* dv4 = dv3 + n3;
  int* S = (int*)(dv4 + n4);
  int* histA = S;                         // NTA
  int* psumA = histA + NTA;               // 2048 (need nbsA=1370)
  int* psumA2 = psumA + 2048;             // 64
  int* boffsA = psumA2 + 64;              // NBA+1
  int* histB = boffsA + (NBA + 1);        // NTB
  int* psumB = histB + NTB;               // 2048 (need nbsB=1564)
  int* psumB2 = psumB + 2048;             // 64
  int* boffsB = psumB2 + 64;              // NB4+1

  // ---------------- partition layers 1-3 (batched chain, staged scatter) ----------------
  part_hist3_kernel<<<NBLK, 1024, 0, stream>>>(ei + E1, ps2 + E2, ps1 + E3, histA,
                                               E1, E12, ETA, chunk3, NBA, B2b, B3b);
  scan_block_kernel<<<nbsA, 256, 0, stream>>>(histA, histA, psumA, NTA);
  scan_block_kernel<<<nbsA2, 256, 0, stream>>>(psumA, psumA, psumA2, nbsA);
  scan_psum_kernel<<<1, 1024, 0, stream>>>(psumA2, nbsA2);
  scan_add_kernel<<<nbsA2, 256, 0, stream>>>(psumA, psumA2, nbsA);
  scan_add_kernel<<<nbsA, 256, 0, stream>>>(histA, psumA, NTA);
  extract_offs_kernel<<<cdiv(NBA + 1, 256), 256, 0, stream>>>(histA, boffsA, NBA, ETA);
  part_scatter3_staged<5472, 688><<<NBLK, 1024, 0, stream>>>(
      ei, ei + E1, ps2, ps2 + E2, ps1, ps1 + E3, histA, binsA,
      E1, E12, ETA, chunk3, NBA, B2b, B3b);
  csrifyA_kernel<<<NBA, 256, 0, stream>>>(binsA, boffsA, no1, no2, no3,
                                          dv1, dv2, dv3, n1, n2, n3, NB1, NB2, NB3);

  // layer-4 hist+scan upfront (touches only S region)
  part_hist4_kernel<<<NBLK, 1024, 0, stream>>>(ps0 + E4, histB, E4, chunk4, NB4);
  scan_block_kernel<<<nbsB, 256, 0, stream>>>(histB, histB, psumB, NTB);
  scan_block_kernel<<<nbsB2, 256, 0, stream>>>(psumB, psumB, psumB2, nbsB);
  scan_psum_kernel<<<1, 1024, 0, stream>>>(psumB2, nbsB2);
  scan_add_kernel<<<nbsB2, 256, 0, stream>>>(psumB, psumB2, nbsB);
  scan_add_kernel<<<nbsB, 256, 0, stream>>>(histB, psumB, NTB);
  extract_offs_kernel<<<cdiv(NB4 + 1, 256), 256, 0, stream>>>(histB, boffsB, NB4, E4);

  // ---------------- Layer 1: h1 (Nx256), out1 ----------------
  gemm_mn<256, 256, 64, 128, 4, false><<<dim3(cdiv(n1, 64), 2), 256, 0, stream>>>(z, W1, h1, n1);
  node_gather4_kernel<256, 0><<<cdiv(n1, 4), 256, 0, stream>>>(binsA, no1, dv1, h1, b1, out1, n1);

  // layer-4 scatter+csrify (binsB overlays dead h1 upper half; after gather1)
  part_scatter4_staged<6256, 784><<<NBLK, 1024, 0, stream>>>(ps0, ps0 + E4, histB, binsB,
                                                             E4, chunk4, NB4);
  csrify4_kernel<<<NB4, 256, 0, stream>>>(binsB, boffsB, no4, dv4, n4, NB4);

  // ---------------- Layer 2: h2 (Nx128), out2 (2N x 128) ----------------
  gemm_mn<256, 128, 64, 128, 4, true><<<dim3(cdiv(N, 64), 1), 256, 0, stream>>>(out1, W2, h2, N);
  node_gather4_kernel<128, 1><<<cdiv(n2, 8), 256, 0, stream>>>(binsA, no2, dv2, h2, b2, out2, n2);

  // ---------------- Layer 3: h3 (2N x 64), out3 (4N x 64) ----------------
  gemm_mn<128, 64, 128, 64, 4, true><<<dim3(cdiv(2 * N, 128), 1), 256, 0, stream>>>(out2, W3, h3, 2 * N);
  node_gather4_kernel<64, 1><<<cdiv(n3, 16), 256, 0, stream>>>(binsA, no3, dv3, h3, b3, out3, n3);

  // ---------------- Layer 4: h4 (4N x 8), out4 = d_out (8N x 8) ----------------
  gemm_small<64, 8, 32, true><<<cdiv(4 * N, 32), 256, 0, stream>>>(out3, W4, h4, 4 * N);
  node_gather4_kernel<8, 1><<<cdiv(n4, 128), 256, 0, stream>>>(binsB, no4, dv4, h4, b4, out, n4);
}